// Round 1
// baseline (560.615 us; speedup 1.0000x reference)
//
#include <hip/hip_runtime.h>
#include <hip/hip_bf16.h>

#define SDTW_N   512
#define SDTW_BW  150
#define BIGF     1e10f

// One block (64 threads = 1 wave) per extended-batch element b in [0,96):
//   b in [0,32):   v_xy = softdtw(x[b], y[b])
//   b in [32,64):  v_xx = softdtw(x[b-32], x[b-32])
//   b in [64,96):  v_yy = softdtw(y[b-64], y[b-64])
// Anti-diagonal wavefront over the banded region (|i-j| <= 150), cost
// recomputed from LDS-cached sequences, 3 rotating LDS rows with BIG guards.
__global__ __launch_bounds__(64) void sdtw_wavefront_kernel(
    const float* __restrict__ x,   // action_trajectory [32,512,4]
    const float* __restrict__ y,   // ground_truth      [32,512,4]
    float* __restrict__ v_out)     // [96]
{
  const int b = blockIdx.x;
  const float* xs;
  const float* ys;
  if (b < 32)      { xs = x + (size_t)b       * SDTW_N * 4; ys = y + (size_t)b * SDTW_N * 4; }
  else if (b < 64) { xs = x + (size_t)(b - 32) * SDTW_N * 4; ys = xs; }
  else             { xs = y + (size_t)(b - 64) * SDTW_N * 4; ys = xs; }

  __shared__ float4 sx[SDTW_N];
  __shared__ float4 sy[SDTW_N];
  __shared__ float  buf[3][SDTW_N + 2];   // index i+1; guards at window edges

  const int t = threadIdx.x;
  for (int i = t; i < SDTW_N; i += 64) {
    sx[i] = ((const float4*)xs)[i];
    sy[i] = ((const float4*)ys)[i];
  }
  for (int i = t; i < 3 * (SDTW_N + 2); i += 64) (&buf[0][0])[i] = BIGF;
  __syncthreads();

  float* d2  = buf[0];  // diag p-2
  float* d1  = buf[1];  // diag p-1
  float* cur = buf[2];  // diag p

  for (int p = 0; p < 2 * SDTW_N - 1; ++p) {
    // active i-window on this anti-diagonal: valid cell AND |2i-p| <= BW
    int ilo = max(p - (SDTW_N - 1), (p - (SDTW_BW - 1)) / 2);
    if (ilo < 0) ilo = 0;
    int ihi = min(SDTW_N - 1, min(p, (p + SDTW_BW) / 2));

    #pragma unroll
    for (int s = 0; s < 3; ++s) {
      int i = ilo + t + 64 * s;
      if (i <= ihi) {
        int j = p - i;
        float4 xi = sx[i];
        float4 yj = sy[j];
        float D = fabsf(xi.x - yj.x) + fabsf(xi.y - yj.y)
                + fabsf(xi.z - yj.z) + fabsf(xi.w - yj.w);
        // neighbors: diag (i-1,j-1) from d2, up (i-1,j) from d1, left (i,j-1) from d1
        float dn = (i == 0 && j == 0) ? 0.0f : d2[i];      // stored at (i-1)+1
        float up = d1[i];                                  // (i-1)+1
        float lf = d1[i + 1];                              // i+1
        float m  = fminf(dn, fminf(up, lf));
        float ss = __expf((m - dn) * 10.0f)
                 + __expf((m - up) * 10.0f)
                 + __expf((m - lf) * 10.0f);
        cur[i + 1] = D + m - 0.1f * __logf(ss);
      }
    }
    if (t == 0) { cur[ilo] = BIGF; cur[ihi + 2] = BIGF; }  // BIG guards
    __syncthreads();
    float* tmp = d2; d2 = d1; d1 = cur; cur = tmp;
  }
  if (t == 0) v_out[b] = d1[SDTW_N];   // R[N-1, N-1]
}

// Small scalar losses + final combine. Single block.
__global__ __launch_bounds__(64) void sdtw_finalize_kernel(
    const float* __restrict__ at,    // [32,512,4]
    const float* __restrict__ mu,    // [32,64]
    const float* __restrict__ lv,    // [32,64]
    const float* __restrict__ ptc,   // [32,1]
    const float* __restrict__ gt,    // [32,512,4]
    const float* __restrict__ v,     // [96]
    float* __restrict__ out)         // [5]
{
  __shared__ float s_gt[32], s_ps[32], s_kl[32], s_vn[32];
  const int t = threadIdx.x;
  if (t < 32) {
    // KL per batch
    float s = 0.0f;
    for (int z = 0; z < 64; ++z) {
      float m = mu[t * 64 + z];
      float l = lv[t * 64 + z];
      s += 1.0f + l - m * m - __expf(l);
    }
    float kld = -0.5f * s;
    s_kl[t] = fmaxf(kld - 0.5f, 0.0f);

    // transition counts (channel 2)
    float g = 0.0f, ps = 0.0f;
    float pg = gt[(t * 512 + 0) * 4 + 2];
    float a0 = at[(t * 512 + 0) * 4 + 2];
    float pp = 1.0f / (1.0f + __expf(-(a0 - 0.5f) * 10.0f));
    for (int n = 1; n < 512; ++n) {
      float cg = gt[(t * 512 + n) * 4 + 2];
      g += fabsf(cg - pg); pg = cg;
      float ca = at[(t * 512 + n) * 4 + 2];
      float cp = 1.0f / (1.0f + __expf(-(ca - 0.5f) * 10.0f));
      ps += fabsf(cp - pp); pp = cp;
    }
    s_gt[t] = g;
    s_ps[t] = ps;

    // normalized sdtw
    s_vn[t] = v[t] - 0.5f * (v[32 + t] + v[64 + t]);
  }
  __syncthreads();
  if (t == 0) {
    float recon = 0.0f, kl = 0.0f, aux = 0.0f, tr = 0.0f;
    for (int b2 = 0; b2 < 32; ++b2) {
      recon += s_vn[b2];
      kl    += s_kl[b2];
      float d = ptc[b2] - s_gt[b2]; aux += d * d;
      float e = s_ps[b2] - s_gt[b2]; tr  += e * e;
    }
    recon *= (1.0f / 1024.0f);   // mean(diag(v)) over 32x32 = sum/1024
    kl    *= (1.0f / 32.0f);
    aux   *= (1.0f / 32.0f);
    tr    *= (1.0f / 32.0f);
    out[0] = recon + kl + 0.1f * aux + 0.5f * tr;
    out[1] = recon;
    out[2] = kl;
    out[3] = aux;
    out[4] = tr;
  }
}

extern "C" void kernel_launch(void* const* d_in, const int* in_sizes, int n_in,
                              void* d_out, int out_size, void* d_ws, size_t ws_size,
                              hipStream_t stream) {
  const float* at  = (const float*)d_in[0];  // action_trajectory
  const float* mu  = (const float*)d_in[1];  // style_mu
  const float* lv  = (const float*)d_in[2];  // style_logvar
  const float* ptc = (const float*)d_in[3];  // predicted_transition_count
  const float* gt  = (const float*)d_in[4];  // ground_truth
  float* v   = (float*)d_ws;                 // [96] sdtw values
  float* out = (float*)d_out;                // [5]

  sdtw_wavefront_kernel<<<96, 64, 0, stream>>>(at, gt, v);
  sdtw_finalize_kernel<<<1, 64, 0, stream>>>(at, mu, lv, ptc, gt, v, out);
}

// Round 2
// 299.435 us; speedup vs baseline: 1.8722x; 1.8722x over previous
//
#include <hip/hip_runtime.h>
#include <hip/hip_bf16.h>

#define SDTW_N 512
#define BIGF   1e10f
#define PAD    128
#define C1f    14.426950408889634f    // 1/(gamma*ln2), gamma=0.1
#define K1f    0.069314718055994531f  // gamma*ln2

__device__ __forceinline__ float cost4(float4 X, float4 Y) {
  return fabsf(X.x - Y.x) + fabsf(X.y - Y.y) + fabsf(X.z - Y.z) + fabsf(X.w - Y.w);
}

// r = D + softmin_gamma(A,B,C), gamma=0.1, in log2 domain.
__device__ __forceinline__ float sm3(float A, float B, float C, float D) {
  float m  = fminf(fminf(A, B), C);
  float M  = fmaxf(fmaxf(A, B), C);
  float E  = __builtin_amdgcn_fmed3f(A, B, C);
  float mc = m * C1f;
  float e1 = exp2f(fmaf(E, -C1f, mc));   // 2^((m-E)*C1)
  float e2 = exp2f(fmaf(M, -C1f, mc));   // 2^((m-M)*C1)
  float S  = 1.0f + e1 + e2;             // min term is 2^0
  return D + fmaf(__log2f(S), -K1f, m);
}

// One double anti-diagonal step: odd diag p then even diag p+1.
// Band-offset slots: u = 3*lane + s, offset d = 2u - 150 + (p&1), i = ceil(p/2)+u-75.
// Invariant on entry: dB = diag p-1, dA = diag p-2.  On exit: dB = diag p+1, dA = diag p.
template<bool MASKED>
__device__ __forceinline__ void pair_step(
    int p, int& ibase, float (&dA)[3], float (&dB)[3],
    const float4* __restrict__ sxp, const float4* __restrict__ syp, int t,
    bool vO0, bool vO1, bool vO2, bool vE0, bool vE1, bool vE2)
{
  // ---------- odd step p: d1 = dB, d2 = dA, out -> dA ----------
  float d1p2 = __shfl_down(dB[0], 1);   // d1[u+1] for s=2 (from lane+1, s=0)
  ibase += 1;                           // i = ibase + u this pair
  const int i0 = ibase + 3 * t;
  const int j0 = p - i0;

  // shared loads for the pair: X identical for both steps; Y union = j0+1..j0-2
  float4 X0 = sxp[i0], X1 = sxp[i0 + 1], X2 = sxp[i0 + 2];
  float4 Ya = syp[j0 + 1], Yb = syp[j0], Yc = syp[j0 - 1], Yd = syp[j0 - 2];

  {
    float r0 = sm3(dA[0], dB[0], dB[1], cost4(X0, Yb));
    float r1 = sm3(dA[1], dB[1], dB[2], cost4(X1, Yc));
    float r2 = sm3(dA[2], dB[2], d1p2,  cost4(X2, Yd));
    bool k0 = vO0, k1 = vO1, k2 = vO2;
    if (MASKED) {
      int lo = max(0, p - 511), hi = min(511, p);
      k0 = k0 && (i0     >= lo) && (i0     <= hi);
      k1 = k1 && (i0 + 1 >= lo) && (i0 + 1 <= hi);
      k2 = k2 && (i0 + 2 >= lo) && (i0 + 2 <= hi);
    }
    dA[0] = k0 ? r0 : BIGF;
    dA[1] = k1 ? r1 : BIGF;
    dA[2] = k2 ? r2 : BIGF;
  }

  // ---------- even step p+1: d1 = dA, d2 = dB, out -> dB ----------
  float d1m0 = __shfl_up(dA[2], 1);     // d1[u-1] for s=0 (from lane-1, s=2)
  if (t == 0) d1m0 = BIGF;              // u-1 = -1 -> out of band
  const int p1 = p + 1;
  {
    float r0 = sm3(dB[0], d1m0,  dA[0], cost4(X0, Ya));
    float r1 = sm3(dB[1], dA[0], dA[1], cost4(X1, Yb));
    float r2 = sm3(dB[2], dA[1], dA[2], cost4(X2, Yc));
    bool k0 = vE0, k1 = vE1, k2 = vE2;
    if (MASKED) {
      int lo = max(0, p1 - 511), hi = min(511, p1);
      k0 = k0 && (i0     >= lo) && (i0     <= hi);
      k1 = k1 && (i0 + 1 >= lo) && (i0 + 1 <= hi);
      k2 = k2 && (i0 + 2 >= lo) && (i0 + 2 <= hi);
    }
    dB[0] = k0 ? r0 : BIGF;
    dB[1] = k1 ? r1 : BIGF;
    dB[2] = k2 ? r2 : BIGF;
  }
}

__global__ __launch_bounds__(64) void sdtw_diag_kernel(
    const float* __restrict__ x,   // [32,512,4]
    const float* __restrict__ y,   // [32,512,4]
    float* __restrict__ v_out)     // [96]
{
  const int b = blockIdx.x;
  const float* xs;
  const float* ys;
  if (b < 32)      { xs = x + (size_t)b        * SDTW_N * 4; ys = y + (size_t)b * SDTW_N * 4; }
  else if (b < 64) { xs = x + (size_t)(b - 32) * SDTW_N * 4; ys = xs; }
  else             { xs = y + (size_t)(b - 64) * SDTW_N * 4; ys = xs; }

  __shared__ float4 sx[SDTW_N + 2 * PAD];
  __shared__ float4 sy[SDTW_N + 2 * PAD];
  const int t = threadIdx.x;
  for (int i = t; i < SDTW_N; i += 64) {
    sx[PAD + i] = ((const float4*)xs)[i];
    sy[PAD + i] = ((const float4*)ys)[i];
  }
  __syncthreads();
  const float4* sxp = sx + PAD;
  const float4* syp = sy + PAD;

  const int u0 = 3 * t;
  const bool vO0 = (u0     <= 149), vO1 = (u0 + 1 <= 149), vO2 = (u0 + 2 <= 149);
  const bool vE0 = (u0     <= 150), vE1 = (u0 + 1 <= 150), vE2 = (u0 + 2 <= 150);

  float dA[3] = { BIGF, BIGF, BIGF };  // diag p-2
  float dB[3];                         // diag p-1
  {
    // diag 0: only (i,j)=(0,0) at u=75 (lane 25, s=0): R = D(0,0)
    float d00 = cost4(sxp[0], syp[0]);
    dB[0] = (t == 25) ? d00 : BIGF;
    dB[1] = BIGF;
    dB[2] = BIGF;
  }
  int ibase = -75;  // i(u=0) at p=0

  #pragma unroll 1
  for (int p = 1; p <= 149; p += 2)
    pair_step<true >(p, ibase, dA, dB, sxp, syp, t, vO0, vO1, vO2, vE0, vE1, vE2);
  #pragma unroll 1
  for (int p = 151; p <= 871; p += 2)
    pair_step<false>(p, ibase, dA, dB, sxp, syp, t, vO0, vO1, vO2, vE0, vE1, vE2);
  #pragma unroll 1
  for (int p = 873; p <= 1021; p += 2)
    pair_step<true >(p, ibase, dA, dB, sxp, syp, t, vO0, vO1, vO2, vE0, vE1, vE2);

  if (t == 25) v_out[b] = dB[0];  // diag 1022, d=0 -> (511,511)
}

// Small scalar losses + final combine. Single block.
__global__ __launch_bounds__(64) void sdtw_finalize_kernel(
    const float* __restrict__ at,    // [32,512,4]
    const float* __restrict__ mu,    // [32,64]
    const float* __restrict__ lv,    // [32,64]
    const float* __restrict__ ptc,   // [32,1]
    const float* __restrict__ gt,    // [32,512,4]
    const float* __restrict__ v,     // [96]
    float* __restrict__ out)         // [5]
{
  __shared__ float s_gt[32], s_ps[32], s_kl[32], s_vn[32];
  const int t = threadIdx.x;
  if (t < 32) {
    float s = 0.0f;
    for (int z = 0; z < 64; ++z) {
      float m = mu[t * 64 + z];
      float l = lv[t * 64 + z];
      s += 1.0f + l - m * m - __expf(l);
    }
    float kld = -0.5f * s;
    s_kl[t] = fmaxf(kld - 0.5f, 0.0f);

    float g = 0.0f, ps = 0.0f;
    float pg = gt[(t * 512 + 0) * 4 + 2];
    float a0 = at[(t * 512 + 0) * 4 + 2];
    float pp = 1.0f / (1.0f + __expf(-(a0 - 0.5f) * 10.0f));
    for (int n = 1; n < 512; ++n) {
      float cg = gt[(t * 512 + n) * 4 + 2];
      g += fabsf(cg - pg); pg = cg;
      float ca = at[(t * 512 + n) * 4 + 2];
      float cp = 1.0f / (1.0f + __expf(-(ca - 0.5f) * 10.0f));
      ps += fabsf(cp - pp); pp = cp;
    }
    s_gt[t] = g;
    s_ps[t] = ps;
    s_vn[t] = v[t] - 0.5f * (v[32 + t] + v[64 + t]);
  }
  __syncthreads();
  if (t == 0) {
    float recon = 0.0f, kl = 0.0f, aux = 0.0f, tr = 0.0f;
    for (int b2 = 0; b2 < 32; ++b2) {
      recon += s_vn[b2];
      kl    += s_kl[b2];
      float d = ptc[b2] - s_gt[b2]; aux += d * d;
      float e = s_ps[b2] - s_gt[b2]; tr  += e * e;
    }
    recon *= (1.0f / 1024.0f);   // mean(diag(v)) over 32x32 = sum/1024
    kl    *= (1.0f / 32.0f);
    aux   *= (1.0f / 32.0f);
    tr    *= (1.0f / 32.0f);
    out[0] = recon + kl + 0.1f * aux + 0.5f * tr;
    out[1] = recon;
    out[2] = kl;
    out[3] = aux;
    out[4] = tr;
  }
}

extern "C" void kernel_launch(void* const* d_in, const int* in_sizes, int n_in,
                              void* d_out, int out_size, void* d_ws, size_t ws_size,
                              hipStream_t stream) {
  const float* at  = (const float*)d_in[0];  // action_trajectory
  const float* mu  = (const float*)d_in[1];  // style_mu
  const float* lv  = (const float*)d_in[2];  // style_logvar
  const float* ptc = (const float*)d_in[3];  // predicted_transition_count
  const float* gt  = (const float*)d_in[4];  // ground_truth
  float* v   = (float*)d_ws;                 // [96] sdtw values
  float* out = (float*)d_out;                // [5]

  sdtw_diag_kernel<<<96, 64, 0, stream>>>(at, gt, v);
  sdtw_finalize_kernel<<<1, 64, 0, stream>>>(at, mu, lv, ptc, gt, v, out);
}

// Round 3
// 184.199 us; speedup vs baseline: 3.0435x; 1.6256x over previous
//
#include <hip/hip_runtime.h>
#include <hip/hip_bf16.h>

#define SEQ   512
#define LPAD  64
#define RPAD  68
#define TOT   (SEQ + LPAD + RPAD)   // 644 float4 per sequence
#define BIGF  1e10f
#define C1f   14.426950408889634f    // 1/(gamma*ln2), gamma=0.1
#define K1f   0.069314718055994531f  // gamma*ln2

__device__ __forceinline__ float cost4(float4 X, float4 Y) {
  return fabsf(X.x - Y.x) + fabsf(X.y - Y.y) + fabsf(X.z - Y.z) + fabsf(X.w - Y.w);
}

// D + softmin_gamma(A,B,C), gamma=0.1, log2 domain (2 exp2 + 1 log2).
__device__ __forceinline__ float sm3(float A, float B, float C, float D) {
  float m  = fminf(fminf(A, B), C);
  float M  = fmaxf(fmaxf(A, B), C);
  float E  = __builtin_amdgcn_fmed3f(A, B, C);
  float mc = m * C1f;
  float e1 = exp2f(fmaf(E, -C1f, mc));
  float e2 = exp2f(fmaf(M, -C1f, mc));
  float S  = 1.0f + e1 + e2;
  return D + fmaf(__log2f(S), -K1f, m);
}

// One pair of anti-diagonals (odd p=2k+1 then even p=2k+2).
// Slots u = 2*lane + s, u in [0,127]; offset d = 2u-126+(p&1); i = k-62+u.
// Entry: dA = diag p-2, dB = diag p-1.  Exit: dA = diag p, dB = diag p+1.
template<bool MASKED>
__device__ __forceinline__ void pair2(
    int k, int t,
    float& dA0, float& dA1, float& dB0, float& dB1,
    float4& X0, float4& X1, float4& Yp, float4& Y0, float4& Ym,
    const float4* __restrict__ sxp, const float4* __restrict__ syp)
{
  const int i0 = k - 62 + 2 * t;
  const int ja = k + 63 - 2 * t;
  // prefetch next pair's new window elements (addresses independent of DP chain)
  float4 nX = sxp[i0 + 2];
  float4 nY = syp[ja + 2];

  // shuffle for odd step: slot u=2t+1 needs diag p-1 slot u+1 = lane t+1's dB0
  float d1p2 = __shfl_down(dB0, 1);
  if (t == 63) d1p2 = BIGF;

  float cO0 = cost4(X0, Y0);   // (i0,   ja)
  float cO1 = cost4(X1, Ym);   // (i0+1, ja-1)
  float cE0 = cost4(X0, Yp);   // (i0,   ja+1)
  float cE1 = cost4(X1, Y0);   // (i0+1, ja)

  // ---- odd diag p=2k+1 -> dA ----
  float r0 = sm3(dA0, dB0, dB1, cO0);     // local (compute first: covers shuffle)
  float r1 = sm3(dA1, dB1, d1p2, cO1);
  if (MASKED) {
    const int j0 = 2 * k + 1 - i0;
    bool v0 = ((unsigned)i0       <= 511u) && ((unsigned)j0       <= 511u);
    bool v1 = ((unsigned)(i0 + 1) <= 511u) && ((unsigned)(j0 - 1) <= 511u);
    r0 = v0 ? r0 : BIGF;
    r1 = v1 ? r1 : BIGF;
  }
  dA0 = r0; dA1 = r1;

  // shuffle for even step: slot u=2t needs diag p slot u-1 = lane t-1's dA1
  float d1m0 = __shfl_up(dA1, 1);
  if (t == 0) d1m0 = BIGF;

  // ---- even diag p+1=2k+2 -> dB ----
  float s1 = sm3(dB1, dA0, dA1, cE1);     // local first
  float s0 = sm3(dB0, d1m0, dA0, cE0);
  if (MASKED) {
    const int j0 = 2 * k + 2 - i0;
    bool v0 = ((unsigned)i0       <= 511u) && ((unsigned)j0       <= 511u);
    bool v1 = ((unsigned)(i0 + 1) <= 511u) && ((unsigned)(j0 - 1) <= 511u);
    s0 = v0 ? s0 : BIGF;
    s1 = v1 ? s1 : BIGF;
  }
  dB0 = s0; dB1 = s1;

  // slide register windows (next pair: i0+1, ja+1)
  X0 = X1; X1 = nX;
  Ym = Y0; Y0 = Yp; Yp = nY;
}

// Blocks 0..95: banded soft-DTW per extended batch element -> ws[b].
// Block 96: KL + transition-count losses -> ws[96..98]. Runs concurrently.
__global__ __launch_bounds__(256) void sdtw_fused_kernel(
    const float* __restrict__ at,    // [32,512,4]
    const float* __restrict__ mu,    // [32,64]
    const float* __restrict__ lv,    // [32,64]
    const float* __restrict__ ptc,   // [32,1]
    const float* __restrict__ gt,    // [32,512,4]
    float* __restrict__ ws)          // [0..95]=v, [96]=klS, [97]=auxS, [98]=trS
{
  __shared__ float4 sx[TOT];
  __shared__ float4 sy[TOT];
  __shared__ float s_g[32], s_ps[32], s_kl[32];

  const int blk = blockIdx.x;
  const int t   = threadIdx.x;

  if (blk < 96) {
    const float* xs;
    const float* ys;
    if (blk < 32)      { xs = at + (size_t)blk        * SEQ * 4; ys = gt + (size_t)blk * SEQ * 4; }
    else if (blk < 64) { xs = at + (size_t)(blk - 32) * SEQ * 4; ys = xs; }
    else               { xs = gt + (size_t)(blk - 64) * SEQ * 4; ys = xs; }

    // zero pads, load body (256 threads)
    for (int i = t; i < LPAD; i += 256) {
      sx[i] = make_float4(0.f, 0.f, 0.f, 0.f);
      sy[i] = make_float4(0.f, 0.f, 0.f, 0.f);
    }
    for (int i = LPAD + SEQ + t; i < TOT; i += 256) {
      sx[i] = make_float4(0.f, 0.f, 0.f, 0.f);
      sy[i] = make_float4(0.f, 0.f, 0.f, 0.f);
    }
    for (int i = t; i < SEQ; i += 256) {
      sx[LPAD + i] = ((const float4*)xs)[i];
      sy[LPAD + i] = ((const float4*)ys)[i];
    }
    __syncthreads();
    if (t >= 64) return;   // single wave does the wavefront; no more barriers

    const float4* sxp = sx + LPAD;
    const float4* syp = sy + LPAD;

    // init: diag -1 (dA) all BIG; diag 0 (dB): (0,0) at u=63 = lane31,s=1
    float d00 = cost4(sxp[0], syp[0]);
    float dA0 = BIGF, dA1 = BIGF;
    float dB0 = BIGF, dB1 = (t == 31) ? d00 : BIGF;

    // initial register windows for pair k=0: i0 = -62+2t, ja = 63-2t
    float4 X0 = sxp[-62 + 2 * t], X1 = sxp[-61 + 2 * t];
    float4 Yp = syp[64 - 2 * t],  Y0 = syp[63 - 2 * t], Ym = syp[62 - 2 * t];

    #pragma unroll 1
    for (int k = 0; k < 64; ++k)
      pair2<true >(k, t, dA0, dA1, dB0, dB1, X0, X1, Yp, Y0, Ym, sxp, syp);
    #pragma unroll 2
    for (int k = 64; k < 447; ++k)
      pair2<false>(k, t, dA0, dA1, dB0, dB1, X0, X1, Yp, Y0, Ym, sxp, syp);
    #pragma unroll 1
    for (int k = 447; k <= 510; ++k)
      pair2<true >(k, t, dA0, dA1, dB0, dB1, X0, X1, Yp, Y0, Ym, sxp, syp);

    if (t == 31) ws[blk] = dB1;   // diag 1022, u=63 -> (511,511)
    return;
  }

  // ---------- loss block (blk == 96), 256 threads: 8 per batch element ----------
  const int b = t >> 3, seg = t & 7;

  // KL partial: 8 z's per thread
  float s = 0.f;
  {
    const float* mb = mu + b * 64 + seg * 8;
    const float* lb = lv + b * 64 + seg * 8;
    #pragma unroll
    for (int z = 0; z < 8; ++z) {
      float m = mb[z], l = lb[z];
      s += 1.0f + l - m * m - __expf(l);
    }
  }
  s += __shfl_down(s, 4, 8);
  s += __shfl_down(s, 2, 8);
  s += __shfl_down(s, 1, 8);

  // transition-count partials: 64 steps per thread, channel 2
  float g = 0.f, ps = 0.f;
  {
    const int n0 = seg * 64;
    const int nstart = (seg == 0) ? 1 : n0;
    const float* gb = gt + (size_t)b * SEQ * 4 + 2;
    const float* ab = at + (size_t)b * SEQ * 4 + 2;
    float pg = gb[(nstart - 1) * 4];
    float pp = 1.0f / (1.0f + __expf((0.5f - ab[(nstart - 1) * 4]) * 10.0f));
    for (int n = nstart; n < n0 + 64; ++n) {
      float cg = gb[n * 4]; g += fabsf(cg - pg); pg = cg;
      float cp = 1.0f / (1.0f + __expf((0.5f - ab[n * 4]) * 10.0f));
      ps += fabsf(cp - pp); pp = cp;
    }
  }
  g  += __shfl_down(g, 4, 8);  g  += __shfl_down(g, 2, 8);  g  += __shfl_down(g, 1, 8);
  ps += __shfl_down(ps, 4, 8); ps += __shfl_down(ps, 2, 8); ps += __shfl_down(ps, 1, 8);

  if (seg == 0) {
    s_g[b]  = g;
    s_ps[b] = ps;
    s_kl[b] = fmaxf(-0.5f * s - 0.5f, 0.0f);
  }
  __syncthreads();

  if (t < 32) {
    float gv  = s_g[t];
    float kl  = s_kl[t];
    float d   = ptc[t] - gv;  float aux = d * d;
    float e   = s_ps[t] - gv; float tr  = e * e;
    kl  += __shfl_down(kl, 16, 32); aux += __shfl_down(aux, 16, 32); tr += __shfl_down(tr, 16, 32);
    kl  += __shfl_down(kl,  8, 32); aux += __shfl_down(aux,  8, 32); tr += __shfl_down(tr,  8, 32);
    kl  += __shfl_down(kl,  4, 32); aux += __shfl_down(aux,  4, 32); tr += __shfl_down(tr,  4, 32);
    kl  += __shfl_down(kl,  2, 32); aux += __shfl_down(aux,  2, 32); tr += __shfl_down(tr,  2, 32);
    kl  += __shfl_down(kl,  1, 32); aux += __shfl_down(aux,  1, 32); tr += __shfl_down(tr,  1, 32);
    if (t == 0) { ws[96] = kl; ws[97] = aux; ws[98] = tr; }
  }
}

__global__ __launch_bounds__(64) void sdtw_combine_kernel(
    const float* __restrict__ ws, float* __restrict__ out)
{
  const int t = threadIdx.x;
  float vn = 0.f;
  if (t < 32) vn = ws[t] - 0.5f * (ws[32 + t] + ws[64 + t]);
  vn += __shfl_down(vn, 16, 32);
  vn += __shfl_down(vn,  8, 32);
  vn += __shfl_down(vn,  4, 32);
  vn += __shfl_down(vn,  2, 32);
  vn += __shfl_down(vn,  1, 32);
  if (t == 0) {
    float recon = vn * (1.0f / 1024.0f);   // mean(diag(v)) = sum/1024
    float kl    = ws[96] * (1.0f / 32.0f);
    float aux   = ws[97] * (1.0f / 32.0f);
    float tr    = ws[98] * (1.0f / 32.0f);
    out[0] = recon + kl + 0.1f * aux + 0.5f * tr;
    out[1] = recon;
    out[2] = kl;
    out[3] = aux;
    out[4] = tr;
  }
}

extern "C" void kernel_launch(void* const* d_in, const int* in_sizes, int n_in,
                              void* d_out, int out_size, void* d_ws, size_t ws_size,
                              hipStream_t stream) {
  const float* at  = (const float*)d_in[0];
  const float* mu  = (const float*)d_in[1];
  const float* lv  = (const float*)d_in[2];
  const float* ptc = (const float*)d_in[3];
  const float* gt  = (const float*)d_in[4];
  float* ws  = (float*)d_ws;
  float* out = (float*)d_out;

  sdtw_fused_kernel<<<97, 256, 0, stream>>>(at, mu, lv, ptc, gt, ws);
  sdtw_combine_kernel<<<1, 64, 0, stream>>>(ws, out);
}

// Round 4
// 123.663 us; speedup vs baseline: 4.5334x; 1.4895x over previous
//
#include <hip/hip_runtime.h>
#include <hip/hip_bf16.h>

#define SEQ   512
#define LPAD  64
#define RPAD  68
#define TOT   (SEQ + LPAD + RPAD)   // 644 float4 per sequence
#define C1f   14.426950408889634f    // 1/(gamma*ln2), gamma=0.1
#define K1f   0.069314718055994531f  // gamma*ln2

__device__ __forceinline__ float cost4(float4 X, float4 Y) {
  return fabsf(X.x - Y.x) + fabsf(X.y - Y.y) + fabsf(X.z - Y.z) + fabsf(X.w - Y.w);
}

// f64 lane shifts via DPP wave shifts (gfx9 lineage): 2cy VALU, 0-fill at edges.
__device__ __forceinline__ double dshr1(double x) {  // lane t <- lane t+1; lane63 <- 0
  int lo = __builtin_amdgcn_update_dpp(0, __double2loint(x), 0x138, 0xF, 0xF, true);
  int hi = __builtin_amdgcn_update_dpp(0, __double2hiint(x), 0x138, 0xF, 0xF, true);
  return __hiloint2double(hi, lo);
}
__device__ __forceinline__ double dshl1(double x) {  // lane t <- lane t-1; lane0 <- 0
  int lo = __builtin_amdgcn_update_dpp(0, __double2loint(x), 0x130, 0xF, 0xF, true);
  int hi = __builtin_amdgcn_update_dpp(0, __double2hiint(x), 0x130, 0xF, 0xF, true);
  return __hiloint2double(hi, lo);
}
__device__ __forceinline__ double pow2i(int k) {     // 2^k exactly, |k| small
  union { unsigned long long u; double d; } v;
  v.u = ((unsigned long long)(1023 + k)) << 52;
  return v.d;
}

// Exp-domain DP pair: odd diag p=2k+1 then even p=2k+2.
// State: dA = diag p-2, dB = diag p-1 (f64, renormalized). Invalid cell = 0.0.
// Scale bookkeeping: dB scale = dA scale + k2prev; odd diag gets bump k1,
// even diag bump k2 (folded into the exp2f args of P); d2-operand scale fixes
// fold into the fma. Ktot accumulates all applied bumps.
template<bool MASKED>
__device__ __forceinline__ void pair2e(
    int k, int t,
    double& dA0, double& dA1, double& dB0, double& dB1,
    float4& X0, float4& X1, float4& Yp, float4& Y0, float4& Ym,
    const float4* __restrict__ sxp, const float4* __restrict__ syp,
    int& k1, int& k2, int& k2prev, int& Ktot)
{
  const int i0 = k - 62 + 2 * t;
  const int ja = k + 63 - 2 * t;
  // prefetch next pair's window elements (independent of DP chain)
  float4 nX = sxp[i0 + 2];
  float4 nY = syp[ja + 2];

  Ktot += k1 + k2;                  // bumps applied this pair
  const double s2p = pow2i(k2prev); // d2 scale fix for odd diag
  const double s1c = pow2i(k1);     // d2 scale fix for even diag
  const float k1f = (float)k1;
  const float k2f = (float)k2;

  // off-critical-path: P = 2^(-cost*C1 + bump)
  float cO0 = cost4(X0, Y0);   // (i0,   ja)   odd
  float cO1 = cost4(X1, Ym);   // (i0+1, ja-1) odd
  float cE0 = cost4(X0, Yp);   // (i0,   ja+1) even
  float cE1 = cost4(X1, Y0);   // (i0+1, ja)   even
  double Po0 = (double)exp2f(fmaf(cO0, -C1f, k1f));
  double Po1 = (double)exp2f(fmaf(cO1, -C1f, k1f));
  double Pe0 = (double)exp2f(fmaf(cE0, -C1f, k2f));
  double Pe1 = (double)exp2f(fmaf(cE1, -C1f, k2f));

  // ---- odd diag p=2k+1 -> new A ----
  double d1p2 = dshr1(dB0);               // d1[u+1] for slot1 (lane63 -> 0)
  double nA0 = Po0 * fma(dA0, s2p, dB0 + dB1);
  double nA1 = Po1 * fma(dA1, s2p, dB1 + d1p2);
  if (MASKED) {
    const int j0 = 2 * k + 1 - i0;
    bool v0 = ((unsigned)i0       <= 511u) && ((unsigned)j0       <= 511u);
    bool v1 = ((unsigned)(i0 + 1) <= 511u) && ((unsigned)(j0 - 1) <= 511u);
    nA0 = v0 ? nA0 : 0.0;
    nA1 = v1 ? nA1 : 0.0;
  }

  // ---- even diag p=2k+2 -> new B ----
  double d1m0 = dshl1(nA1);               // d1[u-1] for slot0 (lane0 -> 0)
  double nB0 = Pe0 * fma(dB0, s1c, d1m0 + nA0);
  double nB1 = Pe1 * fma(dB1, s1c, nA0 + nA1);
  if (MASKED) {
    const int j0 = 2 * k + 2 - i0;
    bool v0 = ((unsigned)i0       <= 511u) && ((unsigned)j0       <= 511u);
    bool v1 = ((unsigned)(i0 + 1) <= 511u) && ((unsigned)(j0 - 1) <= 511u);
    nB0 = v0 ? nB0 : 0.0;
    nB1 = v1 ? nB1 : 0.0;
  }

  dA0 = nA0; dA1 = nA1; dB0 = nB0; dB1 = nB1;

  // slide register windows (next pair: i0+1, ja+1)
  X0 = X1; X1 = nX;
  Ym = Y0; Y0 = Yp; Yp = nY;

  // renorm decision for NEXT pair: center slot u=63 = lane31's dB1.
  int hibits = __builtin_amdgcn_readlane(__double2hiint(dB1), 31);
  int e  = (hibits >> 20) & 0x7ff;
  int kc = 1023 - e;
  kc = kc < -250 ? -250 : (kc > 250 ? 250 : kc);
  k2prev = k2;
  k1 = kc / 2;
  k2 = kc - k1;
}

// Blocks 0..95: banded soft-DTW per extended batch element -> ws[b].
// Block 96: KL + transition-count losses -> ws[96..98]. Runs concurrently.
__global__ __launch_bounds__(256, 1) void sdtw_fused_kernel(
    const float* __restrict__ at,    // [32,512,4]
    const float* __restrict__ mu,    // [32,64]
    const float* __restrict__ lv,    // [32,64]
    const float* __restrict__ ptc,   // [32,1]
    const float* __restrict__ gt,    // [32,512,4]
    float* __restrict__ ws)          // [0..95]=v, [96]=klS, [97]=auxS, [98]=trS
{
  __shared__ float4 sx[TOT];
  __shared__ float4 sy[TOT];
  __shared__ float s_g[32], s_ps[32], s_kl[32];

  const int blk = blockIdx.x;
  const int t   = threadIdx.x;

  if (blk < 96) {
    const float* xs;
    const float* ys;
    if (blk < 32)      { xs = at + (size_t)blk        * SEQ * 4; ys = gt + (size_t)blk * SEQ * 4; }
    else if (blk < 64) { xs = at + (size_t)(blk - 32) * SEQ * 4; ys = xs; }
    else               { xs = gt + (size_t)(blk - 64) * SEQ * 4; ys = xs; }

    for (int i = t; i < LPAD; i += 256) {
      sx[i] = make_float4(0.f, 0.f, 0.f, 0.f);
      sy[i] = make_float4(0.f, 0.f, 0.f, 0.f);
    }
    for (int i = LPAD + SEQ + t; i < TOT; i += 256) {
      sx[i] = make_float4(0.f, 0.f, 0.f, 0.f);
      sy[i] = make_float4(0.f, 0.f, 0.f, 0.f);
    }
    for (int i = t; i < SEQ; i += 256) {
      sx[LPAD + i] = ((const float4*)xs)[i];
      sy[LPAD + i] = ((const float4*)ys)[i];
    }
    __syncthreads();
    if (t >= 64) return;   // single wave runs the wavefront; no more barriers

    const float4* sxp = sx + LPAD;
    const float4* syp = sy + LPAD;

    // init: diag -1 (dA) = 0; diag 0 (dB): (0,0) at u=63 (lane31, slot1).
    // Split-exponent init keeps E(0,0) in [1,2): stored = 2^(a0-n0), Ktot=-n0.
    float a0 = -C1f * cost4(sxp[0], syp[0]);
    int   n0 = (int)floorf(a0);
    double e00 = (double)exp2f(a0 - (float)n0);
    double dA0 = 0.0, dA1 = 0.0;
    double dB0 = 0.0, dB1 = (t == 31) ? e00 : 0.0;
    int Ktot = -n0;
    int k1 = 0, k2 = 0, k2prev = 0;

    // initial register windows for pair k=0: i0 = -62+2t, ja = 63-2t
    float4 X0 = sxp[-62 + 2 * t], X1 = sxp[-61 + 2 * t];
    float4 Yp = syp[64 - 2 * t],  Y0 = syp[63 - 2 * t], Ym = syp[62 - 2 * t];

    #pragma unroll 1
    for (int k = 0; k < 64; ++k)
      pair2e<true >(k, t, dA0, dA1, dB0, dB1, X0, X1, Yp, Y0, Ym, sxp, syp, k1, k2, k2prev, Ktot);
    #pragma unroll 2
    for (int k = 64; k < 447; ++k)
      pair2e<false>(k, t, dA0, dA1, dB0, dB1, X0, X1, Yp, Y0, Ym, sxp, syp, k1, k2, k2prev, Ktot);
    #pragma unroll 1
    for (int k = 447; k <= 510; ++k)
      pair2e<true >(k, t, dA0, dA1, dB0, dB1, X0, X1, Yp, Y0, Ym, sxp, syp, k1, k2, k2prev, Ktot);

    if (t == 31) {
      // v = -gamma*ln(E_true) = -K1f*(log2(stored) - Ktot)
      unsigned long long bits = __double_as_longlong(dB1);
      int ee = (int)((bits >> 52) & 0x7ffull);
      double mant = __longlong_as_double((bits & 0xFFFFFFFFFFFFFull) | (1023ull << 52));
      double l2 = (double)(ee - 1023) + (double)__log2f((float)mant);
      ws[blk] = (float)(-(double)K1f * (l2 - (double)Ktot));
    }
    return;
  }

  // ---------- loss block (blk == 96), 256 threads: 8 per batch element ----------
  const int b = t >> 3, seg = t & 7;

  float s = 0.f;
  {
    const float* mb = mu + b * 64 + seg * 8;
    const float* lb = lv + b * 64 + seg * 8;
    #pragma unroll
    for (int z = 0; z < 8; ++z) {
      float m = mb[z], l = lb[z];
      s += 1.0f + l - m * m - __expf(l);
    }
  }
  s += __shfl_down(s, 4, 8);
  s += __shfl_down(s, 2, 8);
  s += __shfl_down(s, 1, 8);

  float g = 0.f, ps = 0.f;
  {
    const int n0 = seg * 64;
    const int nstart = (seg == 0) ? 1 : n0;
    const float* gb = gt + (size_t)b * SEQ * 4 + 2;
    const float* ab = at + (size_t)b * SEQ * 4 + 2;
    float pg = gb[(nstart - 1) * 4];
    float pp = 1.0f / (1.0f + __expf((0.5f - ab[(nstart - 1) * 4]) * 10.0f));
    for (int n = nstart; n < n0 + 64; ++n) {
      float cg = gb[n * 4]; g += fabsf(cg - pg); pg = cg;
      float cp = 1.0f / (1.0f + __expf((0.5f - ab[n * 4]) * 10.0f));
      ps += fabsf(cp - pp); pp = cp;
    }
  }
  g  += __shfl_down(g, 4, 8);  g  += __shfl_down(g, 2, 8);  g  += __shfl_down(g, 1, 8);
  ps += __shfl_down(ps, 4, 8); ps += __shfl_down(ps, 2, 8); ps += __shfl_down(ps, 1, 8);

  if (seg == 0) {
    s_g[b]  = g;
    s_ps[b] = ps;
    s_kl[b] = fmaxf(-0.5f * s - 0.5f, 0.0f);
  }
  __syncthreads();

  if (t < 32) {
    float gv  = s_g[t];
    float kl  = s_kl[t];
    float d   = ptc[t] - gv;  float aux = d * d;
    float e   = s_ps[t] - gv; float tr  = e * e;
    kl  += __shfl_down(kl, 16, 32); aux += __shfl_down(aux, 16, 32); tr += __shfl_down(tr, 16, 32);
    kl  += __shfl_down(kl,  8, 32); aux += __shfl_down(aux,  8, 32); tr += __shfl_down(tr,  8, 32);
    kl  += __shfl_down(kl,  4, 32); aux += __shfl_down(aux,  4, 32); tr += __shfl_down(tr,  4, 32);
    kl  += __shfl_down(kl,  2, 32); aux += __shfl_down(aux,  2, 32); tr += __shfl_down(tr,  2, 32);
    kl  += __shfl_down(kl,  1, 32); aux += __shfl_down(aux,  1, 32); tr += __shfl_down(tr,  1, 32);
    if (t == 0) { ws[96] = kl; ws[97] = aux; ws[98] = tr; }
  }
}

__global__ __launch_bounds__(64) void sdtw_combine_kernel(
    const float* __restrict__ ws, float* __restrict__ out)
{
  const int t = threadIdx.x;
  float vn = 0.f;
  if (t < 32) vn = ws[t] - 0.5f * (ws[32 + t] + ws[64 + t]);
  vn += __shfl_down(vn, 16, 32);
  vn += __shfl_down(vn,  8, 32);
  vn += __shfl_down(vn,  4, 32);
  vn += __shfl_down(vn,  2, 32);
  vn += __shfl_down(vn,  1, 32);
  if (t == 0) {
    float recon = vn * (1.0f / 1024.0f);   // mean(diag(v)) = sum/1024
    float kl    = ws[96] * (1.0f / 32.0f);
    float aux   = ws[97] * (1.0f / 32.0f);
    float tr    = ws[98] * (1.0f / 32.0f);
    out[0] = recon + kl + 0.1f * aux + 0.5f * tr;
    out[1] = recon;
    out[2] = kl;
    out[3] = aux;
    out[4] = tr;
  }
}

extern "C" void kernel_launch(void* const* d_in, const int* in_sizes, int n_in,
                              void* d_out, int out_size, void* d_ws, size_t ws_size,
                              hipStream_t stream) {
  const float* at  = (const float*)d_in[0];
  const float* mu  = (const float*)d_in[1];
  const float* lv  = (const float*)d_in[2];
  const float* ptc = (const float*)d_in[3];
  const float* gt  = (const float*)d_in[4];
  float* ws  = (float*)d_ws;
  float* out = (float*)d_out;

  sdtw_fused_kernel<<<97, 256, 0, stream>>>(at, mu, lv, ptc, gt, ws);
  sdtw_combine_kernel<<<1, 64, 0, stream>>>(ws, out);
}

// Round 5
// 118.503 us; speedup vs baseline: 4.7308x; 1.0435x over previous
//
#include <hip/hip_runtime.h>
#include <hip/hip_bf16.h>

#define SEQ   512
#define LPAD  64
#define RPAD  68
#define TOT   (SEQ + LPAD + RPAD)   // 644 float4 per sequence
#define C1f   14.426950408889634f    // 1/(gamma*ln2), gamma=0.1
#define K1f   0.069314718055994531f  // gamma*ln2

__device__ __forceinline__ float cost4(float4 X, float4 Y) {
  return fabsf(X.x - Y.x) + fabsf(X.y - Y.y) + fabsf(X.z - Y.z) + fabsf(X.w - Y.w);
}

// f64 lane shifts via DPP wave shifts: 2cy VALU, 0-fill at edges.
__device__ __forceinline__ double dshr1(double x) {  // lane t <- lane t+1; lane63 <- 0
  int lo = __builtin_amdgcn_update_dpp(0, __double2loint(x), 0x138, 0xF, 0xF, true);
  int hi = __builtin_amdgcn_update_dpp(0, __double2hiint(x), 0x138, 0xF, 0xF, true);
  return __hiloint2double(hi, lo);
}
__device__ __forceinline__ double dshl1(double x) {  // lane t <- lane t-1; lane0 <- 0
  int lo = __builtin_amdgcn_update_dpp(0, __double2loint(x), 0x130, 0xF, 0xF, true);
  int hi = __builtin_amdgcn_update_dpp(0, __double2hiint(x), 0x130, 0xF, 0xF, true);
  return __hiloint2double(hi, lo);
}
__device__ __forceinline__ double pow2i(int k) {     // 2^k exactly, |k| <= ~500
  union { unsigned long long u; double d; } v;
  v.u = ((unsigned long long)(1023 + k)) << 52;
  return v.d;
}

// Exp-domain DP pair: odd diag p=2k+1 then even p=2k+2.
// dA = diag p-2, dB = diag p-1 (renormalized f64). Invalid cell == 0.0.
// bumpA: scale bump applied this pair (decided 2 pairs ago, lag-compensated).
// k2prev: even-diag bump of previous pair (= scale gap between dB and dA).
// Outputs: k2out (this pair's even-diag bump), defOut (center exponent deficit).
template<bool MASKED>
__device__ __forceinline__ void pair2e(
    int k, int t,
    double& dA0, double& dA1, double& dB0, double& dB1,
    float4& X0, float4& X1, float4& Yp, float4& Y0, float4& Ym,
    const float4* __restrict__ pX, const float4* __restrict__ pY,
    int bumpA, int k2prev, int& k2out, int& defOut)
{
  // prefetch next pair's window elements (independent of DP chain)
  float4 nX = pX[k + 2];
  float4 nY = pY[k + 2];

  const int k1 = bumpA >> 1;        // arithmetic split, |k1|,|k2| <= 125
  const int k2 = bumpA - k1;
  const double s2p = pow2i(k2prev); // d2 scale fix, odd diag
  const double s1c = pow2i(k1);     // d2 scale fix, even diag
  const float k1f = (float)k1;
  const float k2f = (float)k2;

  // off-critical-path: P = 2^(-cost*C1 + bump)
  float cO0 = cost4(X0, Y0);   // (i0,   ja)   odd
  float cO1 = cost4(X1, Ym);   // (i0+1, ja-1) odd
  float cE0 = cost4(X0, Yp);   // (i0,   ja+1) even
  float cE1 = cost4(X1, Y0);   // (i0+1, ja)   even
  double Po0 = (double)exp2f(fmaf(cO0, -C1f, k1f));
  double Po1 = (double)exp2f(fmaf(cO1, -C1f, k1f));
  double Pe0 = (double)exp2f(fmaf(cE0, -C1f, k2f));
  double Pe1 = (double)exp2f(fmaf(cE1, -C1f, k2f));

  // ---- odd diag p=2k+1 -> new A ----
  double d1p2 = dshr1(dB0);               // d1[u+1] for slot1 (lane63 -> 0)
  double nA0 = Po0 * fma(dA0, s2p, dB0 + dB1);
  double nA1 = Po1 * fma(dA1, s2p, dB1 + d1p2);
  if (MASKED) {
    const int i0 = k - 62 + 2 * t;
    const int j0 = 2 * k + 1 - i0;
    bool v0 = ((unsigned)i0       <= 511u) && ((unsigned)j0       <= 511u);
    bool v1 = ((unsigned)(i0 + 1) <= 511u) && ((unsigned)(j0 - 1) <= 511u);
    nA0 = v0 ? nA0 : 0.0;
    nA1 = v1 ? nA1 : 0.0;
  }

  // ---- even diag p=2k+2 -> new B ----
  double d1m0 = dshl1(nA1);               // d1[u-1] for slot0 (lane0 -> 0)
  double nB0 = Pe0 * fma(dB0, s1c, d1m0 + nA0);
  double nB1 = Pe1 * fma(dB1, s1c, nA0 + nA1);
  if (MASKED) {
    const int i0 = k - 62 + 2 * t;
    const int j0 = 2 * k + 2 - i0;
    bool v0 = ((unsigned)i0       <= 511u) && ((unsigned)j0       <= 511u);
    bool v1 = ((unsigned)(i0 + 1) <= 511u) && ((unsigned)(j0 - 1) <= 511u);
    nB0 = v0 ? nB0 : 0.0;
    nB1 = v1 ? nB1 : 0.0;
  }

  dA0 = nA0; dA1 = nA1; dB0 = nB0; dB1 = nB1;

  // slide register windows (unrolled loop renames these away)
  X0 = X1; X1 = nX;
  Ym = Y0; Y0 = Yp; Yp = nY;

  k2out = k2;
  // observe center cell (u=63 = lane31 slot1) exponent; consumed 2 pairs later
  int hibits = __builtin_amdgcn_readlane(__double2hiint(dB1), 31);
  defOut = 1023 - ((hibits >> 20) & 0x7ff);
}

#define PAIR_FEEDBACK()                                  \
  do {                                                   \
    Ktot += bq0;                                         \
    int nb = def - bq1;                                  \
    nb = nb < -250 ? -250 : (nb > 250 ? 250 : nb);       \
    bq0 = bq1; bq1 = nb;                                 \
  } while (0)

// Blocks 0..95: banded soft-DTW per extended batch element -> ws[b].
// Block 96: KL + transition-count losses -> ws[96..98]. Runs concurrently.
__global__ __launch_bounds__(256, 1) void sdtw_fused_kernel(
    const float* __restrict__ at,    // [32,512,4]
    const float* __restrict__ mu,    // [32,64]
    const float* __restrict__ lv,    // [32,64]
    const float* __restrict__ ptc,   // [32,1]
    const float* __restrict__ gt,    // [32,512,4]
    float* __restrict__ ws)          // [0..95]=v, [96]=klS, [97]=auxS, [98]=trS
{
  __shared__ float4 sx[TOT];
  __shared__ float4 sy[TOT];
  __shared__ float s_g[32], s_ps[32], s_kl[32];

  const int blk = blockIdx.x;
  const int t   = threadIdx.x;

  if (blk < 96) {
    const float* xs;
    const float* ys;
    if (blk < 32)      { xs = at + (size_t)blk        * SEQ * 4; ys = gt + (size_t)blk * SEQ * 4; }
    else if (blk < 64) { xs = at + (size_t)(blk - 32) * SEQ * 4; ys = xs; }
    else               { xs = gt + (size_t)(blk - 64) * SEQ * 4; ys = xs; }

    for (int i = t; i < LPAD; i += 256) {
      sx[i] = make_float4(0.f, 0.f, 0.f, 0.f);
      sy[i] = make_float4(0.f, 0.f, 0.f, 0.f);
    }
    for (int i = LPAD + SEQ + t; i < TOT; i += 256) {
      sx[i] = make_float4(0.f, 0.f, 0.f, 0.f);
      sy[i] = make_float4(0.f, 0.f, 0.f, 0.f);
    }
    for (int i = t; i < SEQ; i += 256) {
      sx[LPAD + i] = ((const float4*)xs)[i];
      sy[LPAD + i] = ((const float4*)ys)[i];
    }
    __syncthreads();
    if (t >= 64) return;   // single wave runs the wavefront; no more barriers

    const float4* sxp = sx + LPAD;
    const float4* syp = sy + LPAD;
    // per-lane base pointers: pair-k loads become base[k+2] (immediate offsets)
    const float4* pX = sxp + (-62 + 2 * t);
    const float4* pY = syp + (63 - 2 * t);

    // init: diag -1 (dA) = 0; diag 0 (dB): (0,0) at u=63 (lane31, slot1).
    float a0 = -C1f * cost4(sxp[0], syp[0]);
    int   n0 = (int)floorf(a0);
    double e00 = (double)exp2f(a0 - (float)n0);
    double dA0 = 0.0, dA1 = 0.0;
    double dB0 = 0.0, dB1 = (t == 31) ? e00 : 0.0;
    int Ktot = -n0;
    int bq0 = 0, bq1 = 0, k2prev = 0, def = 0;

    // initial register windows for pair k=0: i0 = -62+2t, ja = 63-2t
    float4 X0 = pX[0], X1 = pX[1];
    float4 Yp = pY[1], Y0 = pY[0], Ym = pY[-1];

    #pragma unroll 1
    for (int k = 0; k < 64; ++k) {
      pair2e<true >(k, t, dA0, dA1, dB0, dB1, X0, X1, Yp, Y0, Ym, pX, pY, bq0, k2prev, k2prev, def);
      PAIR_FEEDBACK();
    }
    #pragma unroll 6
    for (int k = 64; k < 447; ++k) {
      pair2e<false>(k, t, dA0, dA1, dB0, dB1, X0, X1, Yp, Y0, Ym, pX, pY, bq0, k2prev, k2prev, def);
      PAIR_FEEDBACK();
    }
    #pragma unroll 1
    for (int k = 447; k <= 510; ++k) {
      pair2e<true >(k, t, dA0, dA1, dB0, dB1, X0, X1, Yp, Y0, Ym, pX, pY, bq0, k2prev, k2prev, def);
      PAIR_FEEDBACK();
    }

    if (t == 31) {
      // v = -gamma*ln(E_true) = -K1f*(log2(stored) - Ktot)
      unsigned long long bits = __double_as_longlong(dB1);
      int ee = (int)((bits >> 52) & 0x7ffull);
      double mant = __longlong_as_double((bits & 0xFFFFFFFFFFFFFull) | (1023ull << 52));
      double l2 = (double)(ee - 1023) + (double)__log2f((float)mant);
      ws[blk] = (float)(-(double)K1f * (l2 - (double)Ktot));
    }
    return;
  }

  // ---------- loss block (blk == 96), 256 threads: 8 per batch element ----------
  const int b = t >> 3, seg = t & 7;

  float s = 0.f;
  {
    const float* mb = mu + b * 64 + seg * 8;
    const float* lb = lv + b * 64 + seg * 8;
    #pragma unroll
    for (int z = 0; z < 8; ++z) {
      float m = mb[z], l = lb[z];
      s += 1.0f + l - m * m - __expf(l);
    }
  }
  s += __shfl_down(s, 4, 8);
  s += __shfl_down(s, 2, 8);
  s += __shfl_down(s, 1, 8);

  float g = 0.f, ps = 0.f;
  {
    const int n0 = seg * 64;
    const int nstart = (seg == 0) ? 1 : n0;
    const float* gb = gt + (size_t)b * SEQ * 4 + 2;
    const float* ab = at + (size_t)b * SEQ * 4 + 2;
    float pg = gb[(nstart - 1) * 4];
    float pp = 1.0f / (1.0f + __expf((0.5f - ab[(nstart - 1) * 4]) * 10.0f));
    for (int n = nstart; n < n0 + 64; ++n) {
      float cg = gb[n * 4]; g += fabsf(cg - pg); pg = cg;
      float cp = 1.0f / (1.0f + __expf((0.5f - ab[n * 4]) * 10.0f));
      ps += fabsf(cp - pp); pp = cp;
    }
  }
  g  += __shfl_down(g, 4, 8);  g  += __shfl_down(g, 2, 8);  g  += __shfl_down(g, 1, 8);
  ps += __shfl_down(ps, 4, 8); ps += __shfl_down(ps, 2, 8); ps += __shfl_down(ps, 1, 8);

  if (seg == 0) {
    s_g[b]  = g;
    s_ps[b] = ps;
    s_kl[b] = fmaxf(-0.5f * s - 0.5f, 0.0f);
  }
  __syncthreads();

  if (t < 32) {
    float gv  = s_g[t];
    float kl  = s_kl[t];
    float d   = ptc[t] - gv;  float aux = d * d;
    float e   = s_ps[t] - gv; float tr  = e * e;
    kl  += __shfl_down(kl, 16, 32); aux += __shfl_down(aux, 16, 32); tr += __shfl_down(tr, 16, 32);
    kl  += __shfl_down(kl,  8, 32); aux += __shfl_down(aux,  8, 32); tr += __shfl_down(tr,  8, 32);
    kl  += __shfl_down(kl,  4, 32); aux += __shfl_down(aux,  4, 32); tr += __shfl_down(tr,  4, 32);
    kl  += __shfl_down(kl,  2, 32); aux += __shfl_down(aux,  2, 32); tr += __shfl_down(tr,  2, 32);
    kl  += __shfl_down(kl,  1, 32); aux += __shfl_down(aux,  1, 32); tr += __shfl_down(tr,  1, 32);
    if (t == 0) { ws[96] = kl; ws[97] = aux; ws[98] = tr; }
  }
}

__global__ __launch_bounds__(64) void sdtw_combine_kernel(
    const float* __restrict__ ws, float* __restrict__ out)
{
  const int t = threadIdx.x;
  float vn = 0.f;
  if (t < 32) vn = ws[t] - 0.5f * (ws[32 + t] + ws[64 + t]);
  vn += __shfl_down(vn, 16, 32);
  vn += __shfl_down(vn,  8, 32);
  vn += __shfl_down(vn,  4, 32);
  vn += __shfl_down(vn,  2, 32);
  vn += __shfl_down(vn,  1, 32);
  if (t == 0) {
    float recon = vn * (1.0f / 1024.0f);   // mean(diag(v)) = sum/1024
    float kl    = ws[96] * (1.0f / 32.0f);
    float aux   = ws[97] * (1.0f / 32.0f);
    float tr    = ws[98] * (1.0f / 32.0f);
    out[0] = recon + kl + 0.1f * aux + 0.5f * tr;
    out[1] = recon;
    out[2] = kl;
    out[3] = aux;
    out[4] = tr;
  }
}

extern "C" void kernel_launch(void* const* d_in, const int* in_sizes, int n_in,
                              void* d_out, int out_size, void* d_ws, size_t ws_size,
                              hipStream_t stream) {
  const float* at  = (const float*)d_in[0];
  const float* mu  = (const float*)d_in[1];
  const float* lv  = (const float*)d_in[2];
  const float* ptc = (const float*)d_in[3];
  const float* gt  = (const float*)d_in[4];
  float* ws  = (float*)d_ws;
  float* out = (float*)d_out;

  sdtw_fused_kernel<<<97, 256, 0, stream>>>(at, mu, lv, ptc, gt, ws);
  sdtw_combine_kernel<<<1, 64, 0, stream>>>(ws, out);
}

// Round 6
// 103.255 us; speedup vs baseline: 5.4294x; 1.1477x over previous
//
#include <hip/hip_runtime.h>
#include <hip/hip_bf16.h>

#define SEQ   512
#define LPAD  64
#define RPAD  68
#define TOT   (SEQ + LPAD + RPAD)   // 644 float4 per sequence
#define C1f   14.426950408889634f    // 1/(gamma*ln2), gamma=0.1
#define K1f   0.069314718055994531f  // gamma*ln2

__device__ __forceinline__ float cost4(float4 X, float4 Y) {
  return fabsf(X.x - Y.x) + fabsf(X.y - Y.y) + fabsf(X.z - Y.z) + fabsf(X.w - Y.w);
}

// f64 lane shifts via DPP wave shifts: VALU, 0-fill at edges (0 == exp-domain BIG).
__device__ __forceinline__ double dshr1(double x) {  // lane t <- lane t+1; lane63 <- 0
  int lo = __builtin_amdgcn_update_dpp(0, __double2loint(x), 0x138, 0xF, 0xF, true);
  int hi = __builtin_amdgcn_update_dpp(0, __double2hiint(x), 0x138, 0xF, 0xF, true);
  return __hiloint2double(hi, lo);
}
__device__ __forceinline__ double dshl1(double x) {  // lane t <- lane t-1; lane0 <- 0
  int lo = __builtin_amdgcn_update_dpp(0, __double2loint(x), 0x130, 0xF, 0xF, true);
  int hi = __builtin_amdgcn_update_dpp(0, __double2hiint(x), 0x130, 0xF, 0xF, true);
  return __hiloint2double(hi, lo);
}
__device__ __forceinline__ double pow2i(int k) {     // 2^k exactly, |k| <= ~500
  union { unsigned long long u; double d; } v;
  v.u = ((unsigned long long)(1023 + k)) << 52;
  return v.d;
}

// ---- software-pipeline stage macros (parity-named registers, all static) ----
// windows for pair m: X0=x[i0], X1=x[i0+1], Yp=y[ja+1], Y0=y[ja], Ym=y[ja-1]
#define LOADW(X0,X1,Yp,Y0,Ym,m) do { \
    X0 = pX[(m)];     X1 = pX[(m)+1]; \
    Yp = pY[(m)+1];   Y0 = pY[(m)];   Ym = pY[(m)-1]; } while (0)

// P factors for a pair with scale bump folded into the exp2 arg.
#define COMPP(Po0,Po1,Pe0,Pe1,K1,K2, X0,X1,Yp,Y0,Ym, bump) do { \
    K1 = (bump) >> 1; K2 = (bump) - K1; \
    float _k1f = (float)K1, _k2f = (float)K2; \
    Po0 = (double)exp2f(fmaf(cost4(X0,Y0), -C1f, _k1f)); \
    Po1 = (double)exp2f(fmaf(cost4(X1,Ym), -C1f, _k1f)); \
    Pe0 = (double)exp2f(fmaf(cost4(X0,Yp), -C1f, _k2f)); \
    Pe1 = (double)exp2f(fmaf(cost4(X1,Y0), -C1f, _k2f)); } while (0)

// f64 recurrence for one pair (odd diag then even diag). ~8-op serial chain.
#define CHAIN(Po0,Po1,Pe0,Pe1,K1) do { \
    double _s2p = pow2i(k2prev), _s1c = pow2i(K1); \
    double _d1p2 = dshr1(dB0); \
    double _nA0 = Po0 * fma(dA0, _s2p, dB0 + dB1); \
    double _nA1 = Po1 * fma(dA1, _s2p, dB1 + _d1p2); \
    double _d1m0 = dshl1(_nA1); \
    double _nB0 = Pe0 * fma(dB0, _s1c, _d1m0 + _nA0); \
    double _nB1 = Pe1 * fma(dB1, _s1c, _nA0 + _nA1); \
    dA0 = _nA0; dA1 = _nA1; dB0 = _nB0; dB1 = _nB1; } while (0)

// lag-2 reactive renorm feedback (identical timing to round-5 queue).
#define FEEDBACK(K2cur) do { \
    int _hib = __builtin_amdgcn_readlane(__double2hiint(dB1), 31); \
    int _def = 1023 - ((_hib >> 20) & 0x7ff); \
    Ktot += bq0; \
    int _nb = _def - bq1; _nb = _nb < -250 ? -250 : (_nb > 250 ? 250 : _nb); \
    bq0 = bq1; bq1 = _nb; k2prev = (K2cur); } while (0)

// Blocks 0..95: banded soft-DTW per extended batch element -> ws[b].
// Block 96: KL + transition-count losses -> ws[96..98]. Runs concurrently.
__global__ __launch_bounds__(256, 1) void sdtw_fused_kernel(
    const float* __restrict__ at,    // [32,512,4]
    const float* __restrict__ mu,    // [32,64]
    const float* __restrict__ lv,    // [32,64]
    const float* __restrict__ ptc,   // [32,1]
    const float* __restrict__ gt,    // [32,512,4]
    float* __restrict__ ws)          // [0..95]=v, [96]=klS, [97]=auxS, [98]=trS
{
  __shared__ float4 sx[TOT];
  __shared__ float4 sy[TOT];
  __shared__ float s_g[32], s_ps[32], s_kl[32];

  const int blk = blockIdx.x;
  const int t   = threadIdx.x;

  if (blk < 96) {
    const float* xs;
    const float* ys;
    if (blk < 32)      { xs = at + (size_t)blk        * SEQ * 4; ys = gt + (size_t)blk * SEQ * 4; }
    else if (blk < 64) { xs = at + (size_t)(blk - 32) * SEQ * 4; ys = xs; }
    else               { xs = gt + (size_t)(blk - 64) * SEQ * 4; ys = xs; }

    for (int i = t; i < LPAD; i += 256) {
      sx[i] = make_float4(0.f, 0.f, 0.f, 0.f);
      sy[i] = make_float4(0.f, 0.f, 0.f, 0.f);
    }
    for (int i = LPAD + SEQ + t; i < TOT; i += 256) {
      sx[i] = make_float4(0.f, 0.f, 0.f, 0.f);
      sy[i] = make_float4(0.f, 0.f, 0.f, 0.f);
    }
    for (int i = t; i < SEQ; i += 256) {
      sx[LPAD + i] = ((const float4*)xs)[i];
      sy[LPAD + i] = ((const float4*)ys)[i];
    }
    __syncthreads();
    if (t >= 64) return;   // single wave runs the wavefront; no more barriers

    const float4* sxp = sx + LPAD;
    const float4* syp = sy + LPAD;
    const float4* pX = sxp + (-62 + 2 * t);   // pair-k slot0 cell i = k-62+2t
    const float4* pY = syp + (63 - 2 * t);    // pair-k slot0 cell j = k+63-2t

    // state init: diag -1 (dA) = 0; diag 0 (dB): (0,0) seeded at u=63 (lane31 slot1)
    float a0 = -C1f * cost4(sxp[0], syp[0]);
    int   n0 = (int)floorf(a0);
    double e00 = (double)exp2f(a0 - (float)n0);
    double dA0 = 0.0, dA1 = 0.0;
    double dB0 = 0.0, dB1 = (t == 31) ? e00 : 0.0;
    int Ktot = -n0;
    int bq0 = 0, bq1 = 0, k2prev = 0;

    // pipeline prologue: windows for pairs 0,1; P for pair 0 (bump b0 = 0)
    float4 AX0, AX1, AYp, AY0, AYm;    // parity-A window set
    float4 BX0, BX1, BYp, BY0, BYm;    // parity-B window set
    double PAo0, PAo1, PAe0, PAe1;     // P for even-parity pairs
    double PBo0, PBo1, PBe0, PBe1;     // P for odd-parity pairs
    int k1A, k2A, k1B, k2B;
    LOADW(AX0, AX1, AYp, AY0, AYm, 0);
    LOADW(BX0, BX1, BYp, BY0, BYm, 1);
    COMPP(PAo0, PAo1, PAe0, PAe1, k1A, k2A, AX0, AX1, AYp, AY0, AYm, 0);

    // steady pipeline: iter n = {load W(n+2), compute P(n+1), chain(n), feedback}
    #pragma unroll 1
    for (int g = 0; g < 255; ++g) {
      // n = 2g (parity A)
      LOADW(AX0, AX1, AYp, AY0, AYm, 2 * g + 2);
      COMPP(PBo0, PBo1, PBe0, PBe1, k1B, k2B, BX0, BX1, BYp, BY0, BYm, bq1);
      CHAIN(PAo0, PAo1, PAe0, PAe1, k1A);
      FEEDBACK(k2A);
      // n = 2g+1 (parity B)
      LOADW(BX0, BX1, BYp, BY0, BYm, 2 * g + 3);
      COMPP(PAo0, PAo1, PAe0, PAe1, k1A, k2A, AX0, AX1, AYp, AY0, AYm, bq1);
      CHAIN(PBo0, PBo1, PBe0, PBe1, k1B);
      FEEDBACK(k2B);
    }
    // final pair n = 510 (parity A): chain only
    CHAIN(PAo0, PAo1, PAe0, PAe1, k1A);
    Ktot += bq0;

    if (t == 31) {
      // v = -gamma*ln(E_true) = -K1f*(log2(stored) - Ktot)
      unsigned long long bits = __double_as_longlong(dB1);
      int ee = (int)((bits >> 52) & 0x7ffull);
      double mant = __longlong_as_double((bits & 0xFFFFFFFFFFFFFull) | (1023ull << 52));
      double l2 = (double)(ee - 1023) + (double)__log2f((float)mant);
      ws[blk] = (float)(-(double)K1f * (l2 - (double)Ktot));
    }
    return;
  }

  // ---------- loss block (blk == 96), 256 threads: 8 per batch element ----------
  const int b = t >> 3, seg = t & 7;

  float s = 0.f;
  {
    const float* mb = mu + b * 64 + seg * 8;
    const float* lb = lv + b * 64 + seg * 8;
    #pragma unroll
    for (int z = 0; z < 8; ++z) {
      float m = mb[z], l = lb[z];
      s += 1.0f + l - m * m - __expf(l);
    }
  }
  s += __shfl_down(s, 4, 8);
  s += __shfl_down(s, 2, 8);
  s += __shfl_down(s, 1, 8);

  float g = 0.f, ps = 0.f;
  {
    const int n0 = seg * 64;
    const int nstart = (seg == 0) ? 1 : n0;
    const float* gb = gt + (size_t)b * SEQ * 4 + 2;
    const float* ab = at + (size_t)b * SEQ * 4 + 2;
    float pg = gb[(nstart - 1) * 4];
    float pp = 1.0f / (1.0f + __expf((0.5f - ab[(nstart - 1) * 4]) * 10.0f));
    for (int n = nstart; n < n0 + 64; ++n) {
      float cg = gb[n * 4]; g += fabsf(cg - pg); pg = cg;
      float cp = 1.0f / (1.0f + __expf((0.5f - ab[n * 4]) * 10.0f));
      ps += fabsf(cp - pp); pp = cp;
    }
  }
  g  += __shfl_down(g, 4, 8);  g  += __shfl_down(g, 2, 8);  g  += __shfl_down(g, 1, 8);
  ps += __shfl_down(ps, 4, 8); ps += __shfl_down(ps, 2, 8); ps += __shfl_down(ps, 1, 8);

  if (seg == 0) {
    s_g[b]  = g;
    s_ps[b] = ps;
    s_kl[b] = fmaxf(-0.5f * s - 0.5f, 0.0f);
  }
  __syncthreads();

  if (t < 32) {
    float gv  = s_g[t];
    float kl  = s_kl[t];
    float d   = ptc[t] - gv;  float aux = d * d;
    float e   = s_ps[t] - gv; float tr  = e * e;
    kl  += __shfl_down(kl, 16, 32); aux += __shfl_down(aux, 16, 32); tr += __shfl_down(tr, 16, 32);
    kl  += __shfl_down(kl,  8, 32); aux += __shfl_down(aux,  8, 32); tr += __shfl_down(tr,  8, 32);
    kl  += __shfl_down(kl,  4, 32); aux += __shfl_down(aux,  4, 32); tr += __shfl_down(tr,  4, 32);
    kl  += __shfl_down(kl,  2, 32); aux += __shfl_down(aux,  2, 32); tr += __shfl_down(tr,  2, 32);
    kl  += __shfl_down(kl,  1, 32); aux += __shfl_down(aux,  1, 32); tr += __shfl_down(tr,  1, 32);
    if (t == 0) { ws[96] = kl; ws[97] = aux; ws[98] = tr; }
  }
}

__global__ __launch_bounds__(64) void sdtw_combine_kernel(
    const float* __restrict__ ws, float* __restrict__ out)
{
  const int t = threadIdx.x;
  float vn = 0.f;
  if (t < 32) vn = ws[t] - 0.5f * (ws[32 + t] + ws[64 + t]);
  vn += __shfl_down(vn, 16, 32);
  vn += __shfl_down(vn,  8, 32);
  vn += __shfl_down(vn,  4, 32);
  vn += __shfl_down(vn,  2, 32);
  vn += __shfl_down(vn,  1, 32);
  if (t == 0) {
    float recon = vn * (1.0f / 1024.0f);   // mean(diag(v)) = sum/1024
    float kl    = ws[96] * (1.0f / 32.0f);
    float aux   = ws[97] * (1.0f / 32.0f);
    float tr    = ws[98] * (1.0f / 32.0f);
    out[0] = recon + kl + 0.1f * aux + 0.5f * tr;
    out[1] = recon;
    out[2] = kl;
    out[3] = aux;
    out[4] = tr;
  }
}

extern "C" void kernel_launch(void* const* d_in, const int* in_sizes, int n_in,
                              void* d_out, int out_size, void* d_ws, size_t ws_size,
                              hipStream_t stream) {
  const float* at  = (const float*)d_in[0];
  const float* mu  = (const float*)d_in[1];
  const float* lv  = (const float*)d_in[2];
  const float* ptc = (const float*)d_in[3];
  const float* gt  = (const float*)d_in[4];
  float* ws  = (float*)d_ws;
  float* out = (float*)d_out;

  sdtw_fused_kernel<<<97, 256, 0, stream>>>(at, mu, lv, ptc, gt, ws);
  sdtw_combine_kernel<<<1, 64, 0, stream>>>(ws, out);
}